// Round 2
// baseline (18.828 us; speedup 1.0000x reference)
//
#include <hip/hip_runtime.h>
#include <hip/hip_bf16.h>

#define DIM 1024

// Unified row kernel. Row space (one 64-lane wave per row, 4 rows/block):
//   rows [0, n_ent)              : escore[row] = ent[row] . Ws[D:]
//   rows [n_ent, n_ent+2D)       : k = row-n_ent; qcontrib = c[k] * (Wq[k] . Ws[:D])
//                                  where c = cat(ent[s], rel[r])
//   row  n_ent+2D                : qcontrib = bq . Ws[:D]
// q-rows accumulate per-block into qpart[bid - erow_blocks] (513 slots).
// Requires n_ent % 4 == 0 (10000) so blocks never straddle categories.
__global__ void k_prep(const int* __restrict__ subject,
                       const int* __restrict__ relation,
                       const float* __restrict__ ent,
                       const float* __restrict__ rel,
                       const float* __restrict__ Wq,
                       const float* __restrict__ bq,
                       const float* __restrict__ Ws,
                       float* __restrict__ qpart,
                       float* __restrict__ escore,
                       int n_ent, int erow_blocks) {
    const int bid  = blockIdx.x;
    const int tid  = threadIdx.x;
    const int wid  = tid >> 6;
    const int lane = tid & 63;
    const int row  = bid * 4 + wid;

    __shared__ float sp[4];
    float qval = 0.f;
    bool  is_q = false;

    if (row < n_ent) {
        // ---- entity row: escore[row] = ent[row] . Ws[D:] ----
        const float* rp = ent + (size_t)row * DIM;
        const float* wc = Ws + DIM;
        float acc = 0.f;
#pragma unroll
        for (int it = 0; it < 4; ++it) {
            const int j = (it * 64 + lane) * 4;
            float4 a = *(const float4*)(rp + j);
            float4 w = *(const float4*)(wc + j);
            acc += a.x * w.x + a.y * w.y + a.z * w.z + a.w * w.w;
        }
#pragma unroll
        for (int off = 32; off; off >>= 1) acc += __shfl_down(acc, off, 64);
        if (lane == 0) escore[row] = acc;
    } else if (row < n_ent + 2 * DIM) {
        // ---- Wq row k: c[k] * (Wq[k] . Ws[:D]) ----
        is_q = true;
        const int k = row - n_ent;
        const float c = (k < DIM) ? ent[(size_t)subject[0] * DIM + k]
                                  : rel[(size_t)relation[0] * DIM + (k - DIM)];
        const float* rp = Wq + (size_t)k * DIM;
        const float* wc = Ws;
        float acc = 0.f;
#pragma unroll
        for (int it = 0; it < 4; ++it) {
            const int j = (it * 64 + lane) * 4;
            float4 a = *(const float4*)(rp + j);
            float4 w = *(const float4*)(wc + j);
            acc += a.x * w.x + a.y * w.y + a.z * w.z + a.w * w.w;
        }
#pragma unroll
        for (int off = 32; off; off >>= 1) acc += __shfl_down(acc, off, 64);
        qval = acc * c;
    } else if (row == n_ent + 2 * DIM) {
        // ---- bias row: bq . Ws[:D] ----
        is_q = true;
        const float* wc = Ws;
        float acc = 0.f;
#pragma unroll
        for (int it = 0; it < 4; ++it) {
            const int j = (it * 64 + lane) * 4;
            float4 a = *(const float4*)(bq + j);
            float4 w = *(const float4*)(wc + j);
            acc += a.x * w.x + a.y * w.y + a.z * w.z + a.w * w.w;
        }
#pragma unroll
        for (int off = 32; off; off >>= 1) acc += __shfl_down(acc, off, 64);
        qval = acc;
    }

    if (lane == 0) sp[wid] = is_q ? qval : 0.f;
    __syncthreads();
    if (bid >= erow_blocks && tid == 0)
        qpart[bid - erow_blocks] = sp[0] + sp[1] + sp[2] + sp[3];
}

__global__ void k_score(const int* __restrict__ cand,
                        const float* __restrict__ escore,
                        const float* __restrict__ qpart,
                        const float* __restrict__ bs,
                        float* __restrict__ out, int n, int nq) {
    __shared__ float s_qt;
    const int tid = threadIdx.x;
    if (tid < 64) {
        float v = 0.f;
        for (int i = tid; i < nq; i += 64) v += qpart[i];   // same order in every block
#pragma unroll
        for (int off = 32; off; off >>= 1) v += __shfl_down(v, off, 64);
        if (tid == 0) s_qt = v + bs[0];
    }
    __syncthreads();
    const int i = blockIdx.x * blockDim.x + tid;
    if (i < n) {
        const float x = s_qt + escore[cand[i]];
        out[i] = 1.f / (1.f + expf(-x));
    }
}

extern "C" void kernel_launch(void* const* d_in, const int* in_sizes, int n_in,
                              void* d_out, int out_size, void* d_ws, size_t ws_size,
                              hipStream_t stream) {
    const int*   subject  = (const int*)d_in[0];
    const int*   relation = (const int*)d_in[1];
    const int*   cand     = (const int*)d_in[2];
    const float* ent      = (const float*)d_in[3];
    const float* rel      = (const float*)d_in[4];
    const float* Wq       = (const float*)d_in[5];
    const float* bq       = (const float*)d_in[6];
    const float* Ws       = (const float*)d_in[7];
    const float* bs       = (const float*)d_in[8];

    const int n_ent  = in_sizes[3] / DIM;          // 10000
    const int n_cand = in_sizes[2];                // 131072

    float* qpart  = (float*)d_ws;                  // 513 floats
    float* escore = qpart + 1024;                  // n_ent floats

    const int erow_blocks = n_ent / 4;             // 2500 (n_ent % 4 == 0)
    const int qrow_blocks = (2 * DIM) / 4 + 1;     // 512 Wq blocks + 1 bq block
    const int nq = qrow_blocks;                    // 513 partials

    k_prep<<<erow_blocks + qrow_blocks, 256, 0, stream>>>(
        subject, relation, ent, rel, Wq, bq, Ws, qpart, escore,
        n_ent, erow_blocks);
    k_score<<<(n_cand + 255) / 256, 256, 0, stream>>>(
        cand, escore, qpart, bs, (float*)d_out, n_cand, nq);
}